// Round 8
// baseline (2720.482 us; speedup 1.0000x reference)
//
#include <hip/hip_runtime.h>
#include <stdint.h>

#define NB 16
#define NM 64
#define NS 256
#define NE 256
#define NH 256

// ---------------- threefry2x32 (jax-exact) ----------------
__device__ __forceinline__ uint32_t rotl32(uint32_t v, int d) { return (v << d) | (v >> (32 - d)); }

__device__ __forceinline__ void threefry(uint32_t k0, uint32_t k1,
                                         uint32_t x0, uint32_t x1,
                                         uint32_t& o0, uint32_t& o1) {
  uint32_t ks2 = k0 ^ k1 ^ 0x1BD11BDAu;
#define TFR(r) { x0 += x1; x1 = rotl32(x1, r); x1 ^= x0; }
  x0 += k0; x1 += k1;
  TFR(13) TFR(15) TFR(26) TFR(6)
  x0 += k1;  x1 += ks2 + 1u;
  TFR(17) TFR(29) TFR(16) TFR(24)
  x0 += ks2; x1 += k0 + 2u;
  TFR(13) TFR(15) TFR(26) TFR(6)
  x0 += k0;  x1 += k1 + 3u;
  TFR(17) TFR(29) TFR(16) TFR(24)
  x0 += k1;  x1 += ks2 + 4u;
  TFR(13) TFR(15) TFR(26) TFR(6)
  x0 += ks2; x1 += k0 + 5u;
#undef TFR
  o0 = x0; o1 = x1;
}

__device__ __forceinline__ float gumbel_from_bits(uint32_t bits) {
  float u = __uint_as_float((bits >> 9) | 0x3f800000u) - 1.0f;
  u = fmaxf(u, 1.17549435e-38f);
  return -logf(-logf(u));
}

__global__ void gumbel_kernel(float* __restrict__ g) {
  const int blk = blockIdx.x;       // b*64 + i
  const int b = blk >> 6;
  const int i = blk & 63;
  const int s = threadIdx.x;        // 0..255
  uint32_t kb0, kb1, f0, f1, r0, r1;
  threefry(0u, 42u, 0u, (uint32_t)b, kb0, kb1);
  threefry(kb0, kb1, 0u, (uint32_t)i, f0, f1);
  threefry(f0, f1, 0u, (uint32_t)s, r0, r1);
  g[(blk << 8) + s] = gumbel_from_bits(r0 ^ r1);
}

// ---------------- per-batch prep ----------------
__global__ void prep_kernel(const float* __restrict__ emb,
                            const float* __restrict__ init_w,
                            const float* __restrict__ Whc,
                            const float* __restrict__ bhc,
                            const float* __restrict__ Wv,
                            const float* __restrict__ bv,
                            const float* __restrict__ Wq,
                            float* __restrict__ qbase,
                            float* __restrict__ q0W) {
  const int b = blockIdx.x, t = threadIdx.x;
  __shared__ float mean_s[NE];
  __shared__ float hbpb[NE];
  __shared__ float iwv[NE];
  const float* eb = emb + (size_t)b * NS * NE;
  float acc = 0.f;
  for (int s = 0; s < NS; ++s) acc += eb[s * NE + t];
  mean_s[t] = acc * (1.0f / NS);
  __syncthreads();
  float h = bhc[t];
  for (int j = 0; j < NE; ++j) h = fmaf(mean_s[j], Whc[j * NE + t], h);
  hbpb[t] = h + bv[t];
  float a2 = 0.f;
  for (int j = 0; j < 2 * NE; ++j) a2 = fmaf(init_w[j], Wv[j * NE + t], a2);
  iwv[t] = a2;
  __syncthreads();
  float qb = 0.f, q0 = 0.f;
  for (int e = 0; e < NE; ++e) {
    float w = Wq[e * NH + t];
    qb = fmaf(hbpb[e], w, qb);
    q0 = fmaf(hbpb[e] + iwv[e], w, q0);
  }
  qbase[b * NH + t] = qb;
  q0W[b * NH + t] = q0;
}

// ---------------- generic row-block GEMM ----------------
__global__ void mm_kernel(const float* __restrict__ A,
                          const float* __restrict__ W,
                          float* __restrict__ C) {
  const int t = threadIdx.x;
  const int hq = (t & 63) * 4;
  const int r0 = (t >> 6) * 4;
  const int rowbase = blockIdx.x * 16;
  float acc[4][4] = {};
  #pragma unroll 2
  for (int e = 0; e < NE; ++e) {
    float4 w = *(const float4*)(W + e * NH + hq);
    #pragma unroll
    for (int r = 0; r < 4; ++r) {
      float a = A[(size_t)(rowbase + r0 + r) * NE + e];
      acc[r][0] = fmaf(a, w.x, acc[r][0]);
      acc[r][1] = fmaf(a, w.y, acc[r][1]);
      acc[r][2] = fmaf(a, w.z, acc[r][2]);
      acc[r][3] = fmaf(a, w.w, acc[r][3]);
    }
  }
  #pragma unroll
  for (int r = 0; r < 4; ++r)
    *(float4*)(C + (size_t)(rowbase + r0 + r) * NH + hq) =
        make_float4(acc[r][0], acc[r][1], acc[r][2], acc[r][3]);
}

#define PIDX(h) (((h) >> 5) * 36 + ((h) & 31))

// ================= ABLATION A: phase-A only, amplified 384 iters =================
// Measures: tanh/exp/rcp u-loop + LDS q/v reads + shfl + hc==0 logit writes + 2 barriers.
// qWp perturbed per-iter via LDS (loop-carried dep; prevents hoisting). No masking.
#define NITER_A 384
__global__ __launch_bounds__(1024, 4) void ablA_kernel(
    const float* __restrict__ kp_g, const float* __restrict__ vptr,
    const float* __restrict__ q0W_g, const float* __restrict__ g_g,
    float* __restrict__ scratch) {
  const int b = blockIdx.x;
  const int tid = threadIdx.x;
  const int hc = tid & 7;
  const int pr = tid >> 3;
  const int s0 = pr * 2, s1 = s0 + 1;

  __shared__ float qWp[8 * 36];
  __shared__ float vpp[8 * 36];
  __shared__ float lg_s[NS];
  __shared__ float val_s[NS];

  float4 kp0[8], kp1[8];
  {
    const float4* p0 = (const float4*)(kp_g + ((size_t)b * NS + s0) * NH + hc * 32);
    const float4* p1 = (const float4*)(kp_g + ((size_t)b * NS + s1) * NH + hc * 32);
    #pragma unroll
    for (int j = 0; j < 8; ++j) {
      float4 a = p0[j], c = p1[j];
      kp0[j] = make_float4(2.f * a.x, 2.f * a.y, 2.f * a.z, 2.f * a.w);
      kp1[j] = make_float4(2.f * c.x, 2.f * c.y, 2.f * c.z, 2.f * c.w);
    }
  }
  float Vsum = 0.f;
  {
    const float4* vv = (const float4*)(vptr + hc * 32);
    #pragma unroll
    for (int j = 0; j < 8; ++j) { float4 v = vv[j]; Vsum += (v.x + v.y) + (v.z + v.w); }
  }
  if (tid < NH) {
    vpp[PIDX(tid)] = -2.0f * vptr[tid];
    qWp[PIDX(tid)] = 2.0f * q0W_g[b * NH + tid];
  }
  const float* gb = g_g + (size_t)b * NM * NS;
  float u_acc = 0.f;
  __syncthreads();

  for (int i = 0; i < NITER_A; ++i) {
    float2 g01 = make_float2(0.f, 0.f);
    if (hc == 0) g01 = *(const float2*)(gb + (i & 63) * NS + s0);
    const float4* q4 = (const float4*)(qWp + hc * 36);
    const float4* v4 = (const float4*)(vpp + hc * 36);
    float a0 = 0.f, a1 = 0.f;
    #pragma unroll
    for (int j = 0; j < 8; ++j) {
      float4 q = q4[j], v = v4[j], k = kp0[j], l = kp1[j];
      { float y = fminf(q.x + k.x, 88.f), t = __expf(y);
        a0 = fmaf(v.x, __builtin_amdgcn_rcpf(t + 1.f), a0);
        float y2 = fminf(q.x + l.x, 88.f), t2 = __expf(y2);
        a1 = fmaf(v.x, __builtin_amdgcn_rcpf(t2 + 1.f), a1); }
      { float y = fminf(q.y + k.y, 88.f), t = __expf(y);
        a0 = fmaf(v.y, __builtin_amdgcn_rcpf(t + 1.f), a0);
        float y2 = fminf(q.y + l.y, 88.f), t2 = __expf(y2);
        a1 = fmaf(v.y, __builtin_amdgcn_rcpf(t2 + 1.f), a1); }
      { float y = fminf(q.z + k.z, 88.f), t = __expf(y);
        a0 = fmaf(v.z, __builtin_amdgcn_rcpf(t + 1.f), a0);
        float y2 = fminf(q.z + l.z, 88.f), t2 = __expf(y2);
        a1 = fmaf(v.z, __builtin_amdgcn_rcpf(t2 + 1.f), a1); }
      { float y = fminf(q.w + k.w, 88.f), t = __expf(y);
        a0 = fmaf(v.w, __builtin_amdgcn_rcpf(t + 1.f), a0);
        float y2 = fminf(q.w + l.w, 88.f), t2 = __expf(y2);
        a1 = fmaf(v.w, __builtin_amdgcn_rcpf(t2 + 1.f), a1); }
    }
    float u0 = Vsum + a0;
    float u1 = Vsum + a1;
    u0 += __shfl_xor(u0, 1); u0 += __shfl_xor(u0, 2); u0 += __shfl_xor(u0, 4);
    u1 += __shfl_xor(u1, 1); u1 += __shfl_xor(u1, 2); u1 += __shfl_xor(u1, 4);
    if (hc == 0) {
      float lg0 = 10.f * tanhf(u0);
      float lg1 = 10.f * tanhf(u1);
      lg_s[s0] = lg0; val_s[s0] = lg0 + g01.x;
      lg_s[s1] = lg1; val_s[s1] = lg1 + g01.y;
    }
    u_acc += u0 + u1;
    __syncthreads();                              // sync1 analog
    // qW update analog: loop-carried LDS dep (mimics real C->A dependency, prevents hoist)
    if (tid < NH) qWp[PIDX(tid)] = qWp[PIDX(tid)] * 0.9999f + 1e-6f;
    __syncthreads();                              // sync3 analog
  }
  scratch[b * 1024 + tid] = u_acc + lg_s[tid & 255] + val_s[tid & 255];
}

// ================= ABLATION BC: everything EXCEPT phase-A compute, 256 iters =================
// lg/val seeded from gumbel; keeps sentinel/mask logic, wave butterflies, all-thread combine,
// serial thread-0 softmax/logf, QB gather + qW write, 3 barriers.
#define NITER_BC 256
__global__ __launch_bounds__(1024, 4) void ablBC_kernel(
    const float* __restrict__ g_g, const float* __restrict__ QB_g,
    const float* __restrict__ qbase_g, float* __restrict__ scratch) {
  const int b = blockIdx.x;
  const int tid = threadIdx.x;
  const int hc = tid & 7;
  const int pr = tid >> 3;
  const int s0 = pr * 2, s1 = s0 + 1;

  __shared__ float qWp[8 * 36];
  __shared__ float lg_s[NS];
  __shared__ float val_s[NS];
  __shared__ float red_v[4];
  __shared__ int   red_i[4];
  __shared__ float red_ml[4];
  __shared__ float red_e[4];
  __shared__ int   idx_hist[NM];

  float qb_reg = (tid < NH) ? 2.0f * qbase_g[b * NH + tid] : 0.f;
  if (tid < NH) qWp[PIDX(tid)] = qb_reg;
  int m = 0, pend = 0;
  float logp = 0.f, qsum = 0.f;
  const float* gb = g_g + (size_t)b * NM * NS;
  __syncthreads();

  for (int i = 0; i < NITER_BC; ++i) {
    // fake phase A: just the writes (source = gumbel), plus sentinel path
    if (pend) {
      pend = 0;
      if (hc == 0) {
        lg_s[s0] = -1e9f; val_s[s0] = -1e9f;
        lg_s[s1] = -1e9f; val_s[s1] = -1e9f;
      }
    } else if (!m) {
      if (hc == 0) {
        float2 g01 = *(const float2*)(gb + (i & 63) * NS + s0);
        lg_s[s0] = g01.x; val_s[s0] = g01.x + g01.y;
        lg_s[s1] = g01.y; val_s[s1] = g01.y + g01.x * 0.5f;
      }
    }
    __syncthreads();                                    // sync1

    if (tid < NS) {
      float lgl = lg_s[tid];
      float v = val_s[tid]; int vi = tid; float ml = lgl;
      #pragma unroll
      for (int off = 1; off < 64; off <<= 1) {
        float ov = __shfl_xor(v, off);
        int   oi = __shfl_xor(vi, off);
        bool take = (ov > v) || (ov == v && oi < vi);
        v  = take ? ov : v;
        vi = take ? oi : vi;
        ml = fmaxf(ml, __shfl_xor(ml, off));
      }
      float e = __expf(lgl - ml);
      #pragma unroll
      for (int off = 1; off < 64; off <<= 1) e += __shfl_xor(e, off);
      if ((tid & 63) == 0) {
        red_v[tid >> 6] = v; red_i[tid >> 6] = vi;
        red_ml[tid >> 6] = ml; red_e[tid >> 6] = e;
      }
    }
    __syncthreads();                                    // sync2

    float bvv = red_v[0]; int bii = red_i[0];
    #pragma unroll
    for (int w = 1; w < 4; ++w) {
      bool take = (red_v[w] > bvv) || (red_v[w] == bvv && red_i[w] < bii);
      bvv = take ? red_v[w] : bvv;
      bii = take ? red_i[w] : bii;
    }
    const int idx = bii;
    if (tid == 0) {
      float ml = fmaxf(fmaxf(red_ml[0], red_ml[1]), fmaxf(red_ml[2], red_ml[3]));
      float sum = 0.f;
      #pragma unroll
      for (int w = 0; w < 4; ++w) sum += red_e[w] * __expf(red_ml[w] - ml);
      logp += lg_s[idx] - (ml + logf(sum));
      idx_hist[i & 63] = idx;
    }
    if (!m && (pr >> 1) == (idx >> 2)) { m = 1; pend = 1; }

    if (tid < NH) {
      float qv = QB_g[((size_t)b * NS + idx) * NH + tid];
      qsum += qv;                                        // keeps every load live
      qWp[PIDX(tid)] = qb_reg + 2.0f * qv;
    }
    __syncthreads();                                    // sync3
  }
  scratch[b * 1024 + tid] = logp + qsum + qWp[PIDX(tid & 255)] + (float)idx_hist[tid & 63];
}

// ---------------- real decode (IDENTICAL to R7) ----------------
__global__ __launch_bounds__(1024, 4) void decode_kernel(
    const float* __restrict__ emb,
    const float* __restrict__ node,
    const float* __restrict__ costs,
    const float* __restrict__ Wv,
    const float* __restrict__ Wq,
    const float* __restrict__ vptr,
    const float* __restrict__ g_g,
    const float* __restrict__ kp_g,
    const float* __restrict__ QB_g,
    const float* __restrict__ qbase_g,
    const float* __restrict__ q0W_g,
    float* __restrict__ out) {
  const int b = blockIdx.x;
  const int tid = threadIdx.x;
  const int hc = tid & 7;
  const int pr = tid >> 3;
  const int s0 = pr * 2, s1 = s0 + 1;

  __shared__ float qWp[8 * 36];
  __shared__ float vpp[8 * 36];
  __shared__ float lg_s[NS];
  __shared__ float val_s[NS];
  __shared__ float red_v[4];
  __shared__ int   red_i[4];
  __shared__ float red_ml[4];
  __shared__ float red_e[4];
  __shared__ int   idx_hist[NM];
  __shared__ float er[NE];
  __shared__ float Ts[NE];

  float4 kp0[8], kp1[8];
  {
    const float4* p0 = (const float4*)(kp_g + ((size_t)b * NS + s0) * NH + hc * 32);
    const float4* p1 = (const float4*)(kp_g + ((size_t)b * NS + s1) * NH + hc * 32);
    #pragma unroll
    for (int j = 0; j < 8; ++j) {
      float4 a = p0[j], c = p1[j];
      kp0[j] = make_float4(2.f * a.x, 2.f * a.y, 2.f * a.z, 2.f * a.w);
      kp1[j] = make_float4(2.f * c.x, 2.f * c.y, 2.f * c.z, 2.f * c.w);
    }
  }
  float Vsum = 0.f;
  {
    const float4* vv = (const float4*)(vptr + hc * 32);
    #pragma unroll
    for (int j = 0; j < 8; ++j) { float4 v = vv[j]; Vsum += (v.x + v.y) + (v.z + v.w); }
  }
  if (tid < NH) {
    vpp[PIDX(tid)] = -2.0f * vptr[tid];
    qWp[PIDX(tid)] = 2.0f * q0W_g[b * NH + tid];
  }
  float qb_reg = (tid < NH) ? 2.0f * qbase_g[b * NH + tid] : 0.f;

  int m = 0, pend = 0;
  float logp = 0.f;
  const float* gb = g_g + (size_t)b * NM * NS;

  __syncthreads();

  for (int i = 0; i < NM; ++i) {
    if (pend) {
      pend = 0;
      if (hc == 0) {
        lg_s[s0] = -1e9f; val_s[s0] = -1e9f;
        lg_s[s1] = -1e9f; val_s[s1] = -1e9f;
      }
    } else if (!m) {
      float2 g01 = make_float2(0.f, 0.f);
      if (hc == 0) g01 = *(const float2*)(gb + i * NS + s0);
      const float4* q4 = (const float4*)(qWp + hc * 36);
      const float4* v4 = (const float4*)(vpp + hc * 36);
      float a0 = 0.f, a1 = 0.f;
      #pragma unroll
      for (int j = 0; j < 8; ++j) {
        float4 q = q4[j], v = v4[j], k = kp0[j], l = kp1[j];
        { float y = fminf(q.x + k.x, 88.f), t = __expf(y);
          a0 = fmaf(v.x, __builtin_amdgcn_rcpf(t + 1.f), a0);
          float y2 = fminf(q.x + l.x, 88.f), t2 = __expf(y2);
          a1 = fmaf(v.x, __builtin_amdgcn_rcpf(t2 + 1.f), a1); }
        { float y = fminf(q.y + k.y, 88.f), t = __expf(y);
          a0 = fmaf(v.y, __builtin_amdgcn_rcpf(t + 1.f), a0);
          float y2 = fminf(q.y + l.y, 88.f), t2 = __expf(y2);
          a1 = fmaf(v.y, __builtin_amdgcn_rcpf(t2 + 1.f), a1); }
        { float y = fminf(q.z + k.z, 88.f), t = __expf(y);
          a0 = fmaf(v.z, __builtin_amdgcn_rcpf(t + 1.f), a0);
          float y2 = fminf(q.z + l.z, 88.f), t2 = __expf(y2);
          a1 = fmaf(v.z, __builtin_amdgcn_rcpf(t2 + 1.f), a1); }
        { float y = fminf(q.w + k.w, 88.f), t = __expf(y);
          a0 = fmaf(v.w, __builtin_amdgcn_rcpf(t + 1.f), a0);
          float y2 = fminf(q.w + l.w, 88.f), t2 = __expf(y2);
          a1 = fmaf(v.w, __builtin_amdgcn_rcpf(t2 + 1.f), a1); }
      }
      float u0 = Vsum + a0;
      float u1 = Vsum + a1;
      u0 += __shfl_xor(u0, 1); u0 += __shfl_xor(u0, 2); u0 += __shfl_xor(u0, 4);
      u1 += __shfl_xor(u1, 1); u1 += __shfl_xor(u1, 2); u1 += __shfl_xor(u1, 4);
      if (hc == 0) {
        float lg0 = 10.f * tanhf(u0);
        float lg1 = 10.f * tanhf(u1);
        lg_s[s0] = lg0; val_s[s0] = lg0 + g01.x;
        lg_s[s1] = lg1; val_s[s1] = lg1 + g01.y;
      }
    }
    __syncthreads();                                    // sync1

    if (tid < NS) {
      float lgl = lg_s[tid];
      float v = val_s[tid]; int vi = tid; float ml = lgl;
      #pragma unroll
      for (int off = 1; off < 64; off <<= 1) {
        float ov = __shfl_xor(v, off);
        int   oi = __shfl_xor(vi, off);
        bool take = (ov > v) || (ov == v && oi < vi);
        v  = take ? ov : v;
        vi = take ? oi : vi;
        ml = fmaxf(ml, __shfl_xor(ml, off));
      }
      float e = __expf(lgl - ml);
      #pragma unroll
      for (int off = 1; off < 64; off <<= 1) e += __shfl_xor(e, off);
      if ((tid & 63) == 0) {
        red_v[tid >> 6] = v; red_i[tid >> 6] = vi;
        red_ml[tid >> 6] = ml; red_e[tid >> 6] = e;
      }
    }
    __syncthreads();                                    // sync2

    float bvv = red_v[0]; int bii = red_i[0];
    #pragma unroll
    for (int w = 1; w < 4; ++w) {
      bool take = (red_v[w] > bvv) || (red_v[w] == bvv && red_i[w] < bii);
      bvv = take ? red_v[w] : bvv;
      bii = take ? red_i[w] : bii;
    }
    const int idx = bii;

    if (tid == 0) {
      float ml = fmaxf(fmaxf(red_ml[0], red_ml[1]), fmaxf(red_ml[2], red_ml[3]));
      float sum = 0.f;
      #pragma unroll
      for (int w = 0; w < 4; ++w) sum += red_e[w] * __expf(red_ml[w] - ml);
      logp += lg_s[idx] - (ml + logf(sum));
      idx_hist[i] = idx;
      out[2 * NB + b * NM + i] = (float)idx;
    }

    if (!m && (pr >> 1) == (idx >> 2)) { m = 1; pend = 1; }

    if (i == 0) {
      if (tid < NE) er[tid] = emb[((size_t)b * NS + idx) * NE + tid];
      __syncthreads();
      if (tid < NE) {
        float tv = 0.f;
        #pragma unroll 4
        for (int j = 0; j < NE; ++j) tv = fmaf(er[j], Wv[j * NE + tid], tv);
        Ts[tid] = tv;
      }
      __syncthreads();
      if (tid < NE) {
        float qi = 0.f;
        #pragma unroll 4
        for (int e2 = 0; e2 < NE; ++e2) qi = fmaf(Ts[e2], Wq[e2 * NH + tid], qi);
        qb_reg += 2.0f * qi;
      }
    }

    if (tid < NH) qWp[PIDX(tid)] = qb_reg + 2.0f * QB_g[((size_t)b * NS + idx) * NH + tid];
    __syncthreads();                                    // sync3
  }

  if (tid == 0) out[b] = logp;

  if (tid < 64) {
    float term = 0.f;
    if (tid > 0) {
      int id = idx_hist[tid];
      int pv = idx_hist[tid - 1];
      float dx = node[((size_t)b * NS + id) * 4 + 0] - node[((size_t)b * NS + pv) * 4 + 2];
      float dy = node[((size_t)b * NS + id) * 4 + 1] - node[((size_t)b * NS + pv) * 4 + 3];
      term = sqrtf(dx * dx + dy * dy) + costs[(size_t)b * NS + pv] + costs[(size_t)b * NS + id];
    }
    #pragma unroll
    for (int off = 1; off < 64; off <<= 1) term += __shfl_xor(term, off);
    if (tid == 0) out[NB + b] = term;
  }
}

extern "C" void kernel_launch(void* const* d_in, const int* in_sizes, int n_in,
                              void* d_out, int out_size, void* d_ws, size_t ws_size,
                              hipStream_t stream) {
  const float* emb    = (const float*)d_in[0];
  const float* node   = (const float*)d_in[1];
  const float* costs  = (const float*)d_in[4];
  const float* init_w = (const float*)d_in[5];
  const float* Whc    = (const float*)d_in[6];
  const float* bhc    = (const float*)d_in[7];
  const float* Wv     = (const float*)d_in[8];
  const float* bv     = (const float*)d_in[9];
  const float* Wq     = (const float*)d_in[10];
  const float* Wk     = (const float*)d_in[11];
  const float* vptr   = (const float*)d_in[12];
  float* out = (float*)d_out;

  float* ws    = (float*)d_ws;
  float* g     = ws;
  float* kp    = g + NB * NM * NS;
  float* QB    = kp + (size_t)NB * NS * NH;
  float* tmpB  = QB + (size_t)NB * NS * NH;
  float* qbase = tmpB + (size_t)NB * NS * NE;
  float* q0W   = qbase + NB * NH;

  gumbel_kernel<<<NB * NM, 256, 0, stream>>>(g);
  prep_kernel<<<NB, NE, 0, stream>>>(emb, init_w, Whc, bhc, Wv, bv, Wq, qbase, q0W);
  mm_kernel<<<NB * NS / 16, 256, 0, stream>>>(emb, Wk, kp);
  mm_kernel<<<NB * NS / 16, 256, 0, stream>>>(emb, Wv + NE * NE, tmpB);
  mm_kernel<<<NB * NS / 16, 256, 0, stream>>>(tmpB, Wq, QB);
  // ---- diagnostic ablations (write only into tmpB, which is dead after mm3) ----
  ablA_kernel<<<NB, 1024, 0, stream>>>(kp, vptr, q0W, g, tmpB);
  ablBC_kernel<<<NB, 1024, 0, stream>>>(g, QB, qbase, tmpB + NB * 1024);
  // ---- real decode (identical to R7) ----
  decode_kernel<<<NB, 1024, 0, stream>>>(emb, node, costs, Wv, Wq, vptr,
                                         g, kp, QB, qbase, q0W, out);
}

// Round 9
// 418.872 us; speedup vs baseline: 6.4948x; 6.4948x over previous
//
#include <hip/hip_runtime.h>
#include <stdint.h>

#define NB 16
#define NM 64
#define NS 256
#define NE 256
#define NH 256

// ---------------- threefry2x32 (jax-exact) ----------------
__device__ __forceinline__ uint32_t rotl32(uint32_t v, int d) { return (v << d) | (v >> (32 - d)); }

__device__ __forceinline__ void threefry(uint32_t k0, uint32_t k1,
                                         uint32_t x0, uint32_t x1,
                                         uint32_t& o0, uint32_t& o1) {
  uint32_t ks2 = k0 ^ k1 ^ 0x1BD11BDAu;
#define TFR(r) { x0 += x1; x1 = rotl32(x1, r); x1 ^= x0; }
  x0 += k0; x1 += k1;
  TFR(13) TFR(15) TFR(26) TFR(6)
  x0 += k1;  x1 += ks2 + 1u;
  TFR(17) TFR(29) TFR(16) TFR(24)
  x0 += ks2; x1 += k0 + 2u;
  TFR(13) TFR(15) TFR(26) TFR(6)
  x0 += k0;  x1 += k1 + 3u;
  TFR(17) TFR(29) TFR(16) TFR(24)
  x0 += k1;  x1 += ks2 + 4u;
  TFR(13) TFR(15) TFR(26) TFR(6)
  x0 += ks2; x1 += k0 + 5u;
#undef TFR
  o0 = x0; o1 = x1;
}

__device__ __forceinline__ float gumbel_from_bits(uint32_t bits) {
  float u = __uint_as_float((bits >> 9) | 0x3f800000u) - 1.0f;
  u = fmaxf(u, 1.17549435e-38f);
  return -logf(-logf(u));
}

// g[b][i][s] — jax_threefry_partitionable=True chain
__global__ void gumbel_kernel(float* __restrict__ g) {
  const int blk = blockIdx.x;       // b*64 + i
  const int b = blk >> 6;
  const int i = blk & 63;
  const int s = threadIdx.x;        // 0..255
  uint32_t kb0, kb1, f0, f1, r0, r1;
  threefry(0u, 42u, 0u, (uint32_t)b, kb0, kb1);
  threefry(kb0, kb1, 0u, (uint32_t)i, f0, f1);
  threefry(f0, f1, 0u, (uint32_t)s, r0, r1);
  g[(blk << 8) + s] = gumbel_from_bits(r0 ^ r1);
}

// ---------------- per-batch prep ----------------
__global__ void prep_kernel(const float* __restrict__ emb,
                            const float* __restrict__ init_w,
                            const float* __restrict__ Whc,
                            const float* __restrict__ bhc,
                            const float* __restrict__ Wv,
                            const float* __restrict__ bv,
                            const float* __restrict__ Wq,
                            float* __restrict__ qbase,
                            float* __restrict__ q0W) {
  const int b = blockIdx.x, t = threadIdx.x;
  __shared__ float mean_s[NE];
  __shared__ float hbpb[NE];
  __shared__ float iwv[NE];
  const float* eb = emb + (size_t)b * NS * NE;
  float acc = 0.f;
  for (int s = 0; s < NS; ++s) acc += eb[s * NE + t];
  mean_s[t] = acc * (1.0f / NS);
  __syncthreads();
  float h = bhc[t];
  for (int j = 0; j < NE; ++j) h = fmaf(mean_s[j], Whc[j * NE + t], h);
  hbpb[t] = h + bv[t];
  float a2 = 0.f;
  for (int j = 0; j < 2 * NE; ++j) a2 = fmaf(init_w[j], Wv[j * NE + t], a2);
  iwv[t] = a2;
  __syncthreads();
  float qb = 0.f, q0 = 0.f;
  for (int e = 0; e < NE; ++e) {
    float w = Wq[e * NH + t];
    qb = fmaf(hbpb[e], w, qb);
    q0 = fmaf(hbpb[e] + iwv[e], w, q0);
  }
  qbase[b * NH + t] = qb;
  q0W[b * NH + t] = q0;
}

// ---------------- generic row-block GEMM ----------------
__global__ void mm_kernel(const float* __restrict__ A,
                          const float* __restrict__ W,
                          float* __restrict__ C) {
  const int t = threadIdx.x;
  const int hq = (t & 63) * 4;
  const int r0 = (t >> 6) * 4;
  const int rowbase = blockIdx.x * 16;
  float acc[4][4] = {};
  #pragma unroll 2
  for (int e = 0; e < NE; ++e) {
    float4 w = *(const float4*)(W + e * NH + hq);
    #pragma unroll
    for (int r = 0; r < 4; ++r) {
      float a = A[(size_t)(rowbase + r0 + r) * NE + e];
      acc[r][0] = fmaf(a, w.x, acc[r][0]);
      acc[r][1] = fmaf(a, w.y, acc[r][1]);
      acc[r][2] = fmaf(a, w.z, acc[r][2]);
      acc[r][3] = fmaf(a, w.w, acc[r][3]);
    }
  }
  #pragma unroll
  for (int r = 0; r < 4; ++r)
    *(float4*)(C + (size_t)(rowbase + r0 + r) * NH + hq) =
        make_float4(acc[r][0], acc[r][1], acc[r][2], acc[r][3]);
}

// in-place QB -> exp(2*QB)  (one-time; removes exp from decode's inner loop)
__global__ void expqb_kernel(float* __restrict__ QB) {
  const size_t i = (size_t)blockIdx.x * 1024 + threadIdx.x;
  QB[i] = __expf(2.0f * QB[i]);
}

#define PIDX(h) (((h) >> 5) * 36 + ((h) & 31))

// ---------------- sequential decode: 1 block per batch item ----------------
// R8 ablation: phase A = 11.3k of 16.5k cyc/step, ~90% VALU-issue-bound on active CUs;
// v_exp/v_rcp ~16 issue-cyc per wave64 -> trans ops were 76% of phase A.
// This version removes ALL exp from the steady-state step:
//   tanh(q+k): 1/(1+e^{2q}e^{2k});  Ek=e^{2kp} in regs (one-time);
//   e^{2q} = e2qb_reg * EQB[idx][h] (EQB precomputed; one mul per h per step).
// Inner element: z=fmaf(e2q,Ek,1); r=rcp(z); acc=fmaf(-2v,r,acc)  -> 1 trans + 2 VALU.
__global__ __launch_bounds__(1024, 4) void decode_kernel(
    const float* __restrict__ emb,
    const float* __restrict__ node,
    const float* __restrict__ costs,
    const float* __restrict__ Wv,
    const float* __restrict__ Wq,
    const float* __restrict__ vptr,
    const float* __restrict__ g_g,
    const float* __restrict__ kp_g,
    const float* __restrict__ EQB_g,       // = exp(2*QB)
    const float* __restrict__ qbase_g,
    const float* __restrict__ q0W_g,
    float* __restrict__ out) {
  const int b = blockIdx.x;
  const int tid = threadIdx.x;
  const int hc = tid & 7;          // 32-float h-chunk
  const int pr = tid >> 3;         // s-pair 0..127
  const int s0 = pr * 2, s1 = s0 + 1;

  __shared__ float qWp[8 * 36];    // holds e^{2q} (padded chunks)
  __shared__ float vpp[8 * 36];    // holds -2*vptr
  __shared__ float lg_s[NS];
  __shared__ float val_s[NS];
  __shared__ float red_v[4];
  __shared__ int   red_i[4];
  __shared__ float red_ml[4];
  __shared__ float red_e[4];
  __shared__ int   idx_hist[NM];
  __shared__ float er[NE];
  __shared__ float Ts[NE];

  // Ek = exp(2*kp) for 2 s x 32 h (registers, step-invariant)
  float4 ek0[8], ek1[8];
  {
    const float4* p0 = (const float4*)(kp_g + ((size_t)b * NS + s0) * NH + hc * 32);
    const float4* p1 = (const float4*)(kp_g + ((size_t)b * NS + s1) * NH + hc * 32);
    #pragma unroll
    for (int j = 0; j < 8; ++j) {
      float4 a = p0[j], c = p1[j];
      ek0[j] = make_float4(__expf(2.f * a.x), __expf(2.f * a.y), __expf(2.f * a.z), __expf(2.f * a.w));
      ek1[j] = make_float4(__expf(2.f * c.x), __expf(2.f * c.y), __expf(2.f * c.z), __expf(2.f * c.w));
    }
  }
  float Vsum = 0.f;
  {
    const float4* vv = (const float4*)(vptr + hc * 32);
    #pragma unroll
    for (int j = 0; j < 8; ++j) { float4 v = vv[j]; Vsum += (v.x + v.y) + (v.z + v.w); }
  }
  if (tid < NH) {
    vpp[PIDX(tid)] = -2.0f * vptr[tid];
    qWp[PIDX(tid)] = __expf(2.0f * q0W_g[b * NH + tid]);   // e^{2*q0}
  }
  float e2qb = (tid < NH) ? __expf(2.0f * qbase_g[b * NH + tid]) : 0.f;

  int m = 0, pend = 0;
  float logp = 0.f;
  const float* gb = g_g + (size_t)b * NM * NS;

  __syncthreads();

  for (int i = 0; i < NM; ++i) {
    // ---- phase A ----
    if (pend) {
      pend = 0;
      if (hc == 0) {
        lg_s[s0] = -1e9f; val_s[s0] = -1e9f;
        lg_s[s1] = -1e9f; val_s[s1] = -1e9f;
      }
    } else if (!m) {
      float2 g01 = make_float2(0.f, 0.f);
      if (hc == 0) g01 = *(const float2*)(gb + i * NS + s0);
      const float4* q4 = (const float4*)(qWp + hc * 36);   // e^{2q}
      const float4* v4 = (const float4*)(vpp + hc * 36);   // -2v
      float a0 = 0.f, a1 = 0.f;
      #pragma unroll
      for (int j = 0; j < 8; ++j) {
        float4 q = q4[j], v = v4[j], k = ek0[j], l = ek1[j];
        { float z = fmaf(q.x, k.x, 1.f); a0 = fmaf(v.x, __builtin_amdgcn_rcpf(z), a0);
          float z2 = fmaf(q.x, l.x, 1.f); a1 = fmaf(v.x, __builtin_amdgcn_rcpf(z2), a1); }
        { float z = fmaf(q.y, k.y, 1.f); a0 = fmaf(v.y, __builtin_amdgcn_rcpf(z), a0);
          float z2 = fmaf(q.y, l.y, 1.f); a1 = fmaf(v.y, __builtin_amdgcn_rcpf(z2), a1); }
        { float z = fmaf(q.z, k.z, 1.f); a0 = fmaf(v.z, __builtin_amdgcn_rcpf(z), a0);
          float z2 = fmaf(q.z, l.z, 1.f); a1 = fmaf(v.z, __builtin_amdgcn_rcpf(z2), a1); }
        { float z = fmaf(q.w, k.w, 1.f); a0 = fmaf(v.w, __builtin_amdgcn_rcpf(z), a0);
          float z2 = fmaf(q.w, l.w, 1.f); a1 = fmaf(v.w, __builtin_amdgcn_rcpf(z2), a1); }
      }
      float u0 = Vsum + a0;        // u = sum v - 2 sum v*r
      float u1 = Vsum + a1;
      u0 += __shfl_xor(u0, 1); u0 += __shfl_xor(u0, 2); u0 += __shfl_xor(u0, 4);
      u1 += __shfl_xor(u1, 1); u1 += __shfl_xor(u1, 2); u1 += __shfl_xor(u1, 4);
      if (hc == 0) {
        float lg0 = 10.f * tanhf(u0);
        float lg1 = 10.f * tanhf(u1);
        lg_s[s0] = lg0; val_s[s0] = lg0 + g01.x;
        lg_s[s1] = lg1; val_s[s1] = lg1 + g01.y;
      }
    }
    __syncthreads();                                    // sync1

    // ---- phase B: per-wave argmax/max/expsum ----
    if (tid < NS) {
      float lgl = lg_s[tid];
      float v = val_s[tid]; int vi = tid; float ml = lgl;
      #pragma unroll
      for (int off = 1; off < 64; off <<= 1) {
        float ov = __shfl_xor(v, off);
        int   oi = __shfl_xor(vi, off);
        bool take = (ov > v) || (ov == v && oi < vi);
        v  = take ? ov : v;
        vi = take ? oi : vi;
        ml = fmaxf(ml, __shfl_xor(ml, off));
      }
      float e = __expf(lgl - ml);
      #pragma unroll
      for (int off = 1; off < 64; off <<= 1) e += __shfl_xor(e, off);
      if ((tid & 63) == 0) {
        red_v[tid >> 6] = v; red_i[tid >> 6] = vi;
        red_ml[tid >> 6] = ml; red_e[tid >> 6] = e;
      }
    }
    __syncthreads();                                    // sync2

    // ---- phase C ----
    float bvv = red_v[0]; int bii = red_i[0];
    #pragma unroll
    for (int w = 1; w < 4; ++w) {
      bool take = (red_v[w] > bvv) || (red_v[w] == bvv && red_i[w] < bii);
      bvv = take ? red_v[w] : bvv;
      bii = take ? red_i[w] : bii;
    }
    const int idx = bii;

    if (tid == 0) {
      float ml = fmaxf(fmaxf(red_ml[0], red_ml[1]), fmaxf(red_ml[2], red_ml[3]));
      float sum = 0.f;
      #pragma unroll
      for (int w = 0; w < 4; ++w) sum += red_e[w] * __expf(red_ml[w] - ml);
      logp += lg_s[idx] - (ml + logf(sum));
      idx_hist[i] = idx;
      out[2 * NB + b * NM + i] = (float)idx;
    }

    if (!m && (pr >> 1) == (idx >> 2)) { m = 1; pend = 1; }

    // one-time after step 0: fold e^{2*Qinit} into e2qb
    if (i == 0) {
      if (tid < NE) er[tid] = emb[((size_t)b * NS + idx) * NE + tid];
      __syncthreads();
      if (tid < NE) {
        float tv = 0.f;
        #pragma unroll 4
        for (int j = 0; j < NE; ++j) tv = fmaf(er[j], Wv[j * NE + tid], tv);
        Ts[tid] = tv;
      }
      __syncthreads();
      if (tid < NE) {
        float qi = 0.f;
        #pragma unroll 4
        for (int e2 = 0; e2 < NE; ++e2) qi = fmaf(Ts[e2], Wq[e2 * NH + tid], qi);
        e2qb *= __expf(2.0f * qi);
      }
    }

    // next step's e^{2q} = e2qb * exp(2*QB[idx])  (one mul per h, NO exp)
    if (tid < NH) qWp[PIDX(tid)] = e2qb * EQB_g[((size_t)b * NS + idx) * NH + tid];
    __syncthreads();                                    // sync3
  }

  if (tid == 0) out[b] = logp;

  // deferred reward
  if (tid < 64) {
    float term = 0.f;
    if (tid > 0) {
      int id = idx_hist[tid];
      int pv = idx_hist[tid - 1];
      float dx = node[((size_t)b * NS + id) * 4 + 0] - node[((size_t)b * NS + pv) * 4 + 2];
      float dy = node[((size_t)b * NS + id) * 4 + 1] - node[((size_t)b * NS + pv) * 4 + 3];
      term = sqrtf(dx * dx + dy * dy) + costs[(size_t)b * NS + pv] + costs[(size_t)b * NS + id];
    }
    #pragma unroll
    for (int off = 1; off < 64; off <<= 1) term += __shfl_xor(term, off);
    if (tid == 0) out[NB + b] = term;
  }
}

extern "C" void kernel_launch(void* const* d_in, const int* in_sizes, int n_in,
                              void* d_out, int out_size, void* d_ws, size_t ws_size,
                              hipStream_t stream) {
  const float* emb    = (const float*)d_in[0];
  const float* node   = (const float*)d_in[1];
  const float* costs  = (const float*)d_in[4];
  const float* init_w = (const float*)d_in[5];
  const float* Whc    = (const float*)d_in[6];
  const float* bhc    = (const float*)d_in[7];
  const float* Wv     = (const float*)d_in[8];
  const float* bv     = (const float*)d_in[9];
  const float* Wq     = (const float*)d_in[10];
  const float* Wk     = (const float*)d_in[11];
  const float* vptr   = (const float*)d_in[12];
  float* out = (float*)d_out;

  float* ws    = (float*)d_ws;
  float* g     = ws;
  float* kp    = g + NB * NM * NS;
  float* QB    = kp + (size_t)NB * NS * NH;
  float* tmpB  = QB + (size_t)NB * NS * NH;
  float* qbase = tmpB + (size_t)NB * NS * NE;
  float* q0W   = qbase + NB * NH;

  gumbel_kernel<<<NB * NM, 256, 0, stream>>>(g);
  prep_kernel<<<NB, NE, 0, stream>>>(emb, init_w, Whc, bhc, Wv, bv, Wq, qbase, q0W);
  mm_kernel<<<NB * NS / 16, 256, 0, stream>>>(emb, Wk, kp);
  mm_kernel<<<NB * NS / 16, 256, 0, stream>>>(emb, Wv + NE * NE, tmpB);
  mm_kernel<<<NB * NS / 16, 256, 0, stream>>>(tmpB, Wq, QB);
  expqb_kernel<<<(NB * NS * NH) / 1024, 1024, 0, stream>>>(QB);   // QB -> exp(2*QB) in place
  decode_kernel<<<NB, 1024, 0, stream>>>(emb, node, costs, Wv, Wq, vptr,
                                         g, kp, QB, qbase, q0W, out);
}

// Round 10
// 398.780 us; speedup vs baseline: 6.8220x; 1.0504x over previous
//
#include <hip/hip_runtime.h>
#include <stdint.h>

#define NB 16
#define NM 64
#define NS 256
#define NE 256
#define NH 256

// ---------------- threefry2x32 (jax-exact) ----------------
__device__ __forceinline__ uint32_t rotl32(uint32_t v, int d) { return (v << d) | (v >> (32 - d)); }

__device__ __forceinline__ void threefry(uint32_t k0, uint32_t k1,
                                         uint32_t x0, uint32_t x1,
                                         uint32_t& o0, uint32_t& o1) {
  uint32_t ks2 = k0 ^ k1 ^ 0x1BD11BDAu;
#define TFR(r) { x0 += x1; x1 = rotl32(x1, r); x1 ^= x0; }
  x0 += k0; x1 += k1;
  TFR(13) TFR(15) TFR(26) TFR(6)
  x0 += k1;  x1 += ks2 + 1u;
  TFR(17) TFR(29) TFR(16) TFR(24)
  x0 += ks2; x1 += k0 + 2u;
  TFR(13) TFR(15) TFR(26) TFR(6)
  x0 += k0;  x1 += k1 + 3u;
  TFR(17) TFR(29) TFR(16) TFR(24)
  x0 += k1;  x1 += ks2 + 4u;
  TFR(13) TFR(15) TFR(26) TFR(6)
  x0 += ks2; x1 += k0 + 5u;
#undef TFR
  o0 = x0; o1 = x1;
}

__device__ __forceinline__ float gumbel_from_bits(uint32_t bits) {
  float u = __uint_as_float((bits >> 9) | 0x3f800000u) - 1.0f;
  u = fmaxf(u, 1.17549435e-38f);
  return -logf(-logf(u));
}

// g[b][i][s] — jax_threefry_partitionable=True chain
__global__ void gumbel_kernel(float* __restrict__ g) {
  const int blk = blockIdx.x;       // b*64 + i
  const int b = blk >> 6;
  const int i = blk & 63;
  const int s = threadIdx.x;        // 0..255
  uint32_t kb0, kb1, f0, f1, r0, r1;
  threefry(0u, 42u, 0u, (uint32_t)b, kb0, kb1);
  threefry(kb0, kb1, 0u, (uint32_t)i, f0, f1);
  threefry(f0, f1, 0u, (uint32_t)s, r0, r1);
  g[(blk << 8) + s] = gumbel_from_bits(r0 ^ r1);
}

// ---------------- per-batch prep ----------------
__global__ void prep_kernel(const float* __restrict__ emb,
                            const float* __restrict__ init_w,
                            const float* __restrict__ Whc,
                            const float* __restrict__ bhc,
                            const float* __restrict__ Wv,
                            const float* __restrict__ bv,
                            const float* __restrict__ Wq,
                            float* __restrict__ qbase,
                            float* __restrict__ q0W) {
  const int b = blockIdx.x, t = threadIdx.x;
  __shared__ float mean_s[NE];
  __shared__ float hbpb[NE];
  __shared__ float iwv[NE];
  const float* eb = emb + (size_t)b * NS * NE;
  float acc = 0.f;
  for (int s = 0; s < NS; ++s) acc += eb[s * NE + t];
  mean_s[t] = acc * (1.0f / NS);
  __syncthreads();
  float h = bhc[t];
  for (int j = 0; j < NE; ++j) h = fmaf(mean_s[j], Whc[j * NE + t], h);
  hbpb[t] = h + bv[t];
  float a2 = 0.f;
  for (int j = 0; j < 2 * NE; ++j) a2 = fmaf(init_w[j], Wv[j * NE + t], a2);
  iwv[t] = a2;
  __syncthreads();
  float qb = 0.f, q0 = 0.f;
  for (int e = 0; e < NE; ++e) {
    float w = Wq[e * NH + t];
    qb = fmaf(hbpb[e], w, qb);
    q0 = fmaf(hbpb[e] + iwv[e], w, q0);
  }
  qbase[b * NH + t] = qb;
  q0W[b * NH + t] = q0;
}

// ---------------- generic row-block GEMM ----------------
__global__ void mm_kernel(const float* __restrict__ A,
                          const float* __restrict__ W,
                          float* __restrict__ C) {
  const int t = threadIdx.x;
  const int hq = (t & 63) * 4;
  const int r0 = (t >> 6) * 4;
  const int rowbase = blockIdx.x * 16;
  float acc[4][4] = {};
  #pragma unroll 2
  for (int e = 0; e < NE; ++e) {
    float4 w = *(const float4*)(W + e * NH + hq);
    #pragma unroll
    for (int r = 0; r < 4; ++r) {
      float a = A[(size_t)(rowbase + r0 + r) * NE + e];
      acc[r][0] = fmaf(a, w.x, acc[r][0]);
      acc[r][1] = fmaf(a, w.y, acc[r][1]);
      acc[r][2] = fmaf(a, w.z, acc[r][2]);
      acc[r][3] = fmaf(a, w.w, acc[r][3]);
    }
  }
  #pragma unroll
  for (int r = 0; r < 4; ++r)
    *(float4*)(C + (size_t)(rowbase + r0 + r) * NH + hq) =
        make_float4(acc[r][0], acc[r][1], acc[r][2], acc[r][3]);
}

// in-place QB -> exp(2*QB)
__global__ void expqb_kernel(float* __restrict__ QB) {
  const size_t i = (size_t)blockIdx.x * 1024 + threadIdx.x;
  QB[i] = __expf(2.0f * QB[i]);
}

#define PIDX(h) (((h) >> 5) * 36 + ((h) & 31))

// ---------------- sequential decode: 1 block per batch item ----------------
// R9 calibration: v_rcp/v_exp = ~16 issue-cyc per wave64 inst; the 64 rcp/thread/step
// were ~4.1k of the 12k cyc step. This version combines 8 reciprocals into 1 via
// denominator products:  sum_i w_i/z_i over 8 elems = (expansion)/prod(z_i)
//   -> 8 rcp + 248 VALU per thread per step (was 64 rcp + 128 VALU).
// Overflow-safe: z=1+e^{2(q+k)}, 8-product exponent ~N(0,6.5sd) << 88 (fp32 exp limit).
__global__ __launch_bounds__(1024, 4) void decode_kernel(
    const float* __restrict__ emb,
    const float* __restrict__ node,
    const float* __restrict__ costs,
    const float* __restrict__ Wv,
    const float* __restrict__ Wq,
    const float* __restrict__ vptr,
    const float* __restrict__ g_g,
    const float* __restrict__ kp_g,
    const float* __restrict__ EQB_g,       // = exp(2*QB)
    const float* __restrict__ qbase_g,
    const float* __restrict__ q0W_g,
    float* __restrict__ out) {
  const int b = blockIdx.x;
  const int tid = threadIdx.x;
  const int hc = tid & 7;          // 32-float h-chunk
  const int pr = tid >> 3;         // s-pair 0..127
  const int s0 = pr * 2, s1 = s0 + 1;

  __shared__ float qWp[8 * 36];    // e^{2q}
  __shared__ float vpp[8 * 36];    // -2*vptr
  __shared__ float lg_s[NS];
  __shared__ float val_s[NS];
  __shared__ float red_v[4];
  __shared__ int   red_i[4];
  __shared__ float red_ml[4];
  __shared__ float red_e[4];
  __shared__ int   idx_hist[NM];
  __shared__ float er[NE];
  __shared__ float Ts[NE];

  // Ek = exp(2*kp) for 2 s x 32 h (registers, step-invariant)
  float4 ek0[8], ek1[8];
  {
    const float4* p0 = (const float4*)(kp_g + ((size_t)b * NS + s0) * NH + hc * 32);
    const float4* p1 = (const float4*)(kp_g + ((size_t)b * NS + s1) * NH + hc * 32);
    #pragma unroll
    for (int j = 0; j < 8; ++j) {
      float4 a = p0[j], c = p1[j];
      ek0[j] = make_float4(__expf(2.f * a.x), __expf(2.f * a.y), __expf(2.f * a.z), __expf(2.f * a.w));
      ek1[j] = make_float4(__expf(2.f * c.x), __expf(2.f * c.y), __expf(2.f * c.z), __expf(2.f * c.w));
    }
  }
  float Vsum = 0.f;
  {
    const float4* vv = (const float4*)(vptr + hc * 32);
    #pragma unroll
    for (int j = 0; j < 8; ++j) { float4 v = vv[j]; Vsum += (v.x + v.y) + (v.z + v.w); }
  }
  if (tid < NH) {
    vpp[PIDX(tid)] = -2.0f * vptr[tid];
    qWp[PIDX(tid)] = __expf(2.0f * q0W_g[b * NH + tid]);
  }
  float e2qb = (tid < NH) ? __expf(2.0f * qbase_g[b * NH + tid]) : 0.f;

  int m = 0, pend = 0;
  float logp = 0.f;
  const float* gb = g_g + (size_t)b * NM * NS;

  __syncthreads();

  for (int i = 0; i < NM; ++i) {
    // ---- phase A ----
    if (pend) {
      pend = 0;
      if (hc == 0) {
        lg_s[s0] = -1e9f; val_s[s0] = -1e9f;
        lg_s[s1] = -1e9f; val_s[s1] = -1e9f;
      }
    } else if (!m) {
      float2 g01 = make_float2(0.f, 0.f);
      if (hc == 0) g01 = *(const float2*)(gb + i * NS + s0);
      const float4* q4 = (const float4*)(qWp + hc * 36);   // e^{2q}
      const float4* v4 = (const float4*)(vpp + hc * 36);   // w = -2v
      float a0 = 0.f, a1 = 0.f;
      // 8-way combine: per 8 elems, 1 rcp.
      #pragma unroll
      for (int jj = 0; jj < 4; ++jj) {
        float4 qa = q4[2 * jj], qb = q4[2 * jj + 1];
        float4 va = v4[2 * jj], vb = v4[2 * jj + 1];
        // ---- s0 ----
        {
          float4 ka = ek0[2 * jj], kb = ek0[2 * jj + 1];
          float z1 = fmaf(qa.x, ka.x, 1.f), z2 = fmaf(qa.y, ka.y, 1.f);
          float z3 = fmaf(qa.z, ka.z, 1.f), z4 = fmaf(qa.w, ka.w, 1.f);
          float z5 = fmaf(qb.x, kb.x, 1.f), z6 = fmaf(qb.y, kb.y, 1.f);
          float z7 = fmaf(qb.z, kb.z, 1.f), z8 = fmaf(qb.w, kb.w, 1.f);
          float p12 = z1 * z2, p34 = z3 * z4, p56 = z5 * z6, p78 = z7 * z8;
          float p1234 = p12 * p34, p5678 = p56 * p78;
          float r = __builtin_amdgcn_rcpf(p1234 * p5678);
          float t12 = fmaf(va.y, z1, va.x * z2);
          float t34 = fmaf(va.w, z3, va.z * z4);
          float t56 = fmaf(vb.y, z5, vb.x * z6);
          float t78 = fmaf(vb.w, z7, vb.z * z8);
          float T14 = fmaf(t34, p12, t12 * p34);
          float T58 = fmaf(t78, p56, t56 * p78);
          a0 = fmaf(T14 * p5678, r, a0);
          a0 = fmaf(T58 * p1234, r, a0);
        }
        // ---- s1 ----
        {
          float4 ka = ek1[2 * jj], kb = ek1[2 * jj + 1];
          float z1 = fmaf(qa.x, ka.x, 1.f), z2 = fmaf(qa.y, ka.y, 1.f);
          float z3 = fmaf(qa.z, ka.z, 1.f), z4 = fmaf(qa.w, ka.w, 1.f);
          float z5 = fmaf(qb.x, kb.x, 1.f), z6 = fmaf(qb.y, kb.y, 1.f);
          float z7 = fmaf(qb.z, kb.z, 1.f), z8 = fmaf(qb.w, kb.w, 1.f);
          float p12 = z1 * z2, p34 = z3 * z4, p56 = z5 * z6, p78 = z7 * z8;
          float p1234 = p12 * p34, p5678 = p56 * p78;
          float r = __builtin_amdgcn_rcpf(p1234 * p5678);
          float t12 = fmaf(va.y, z1, va.x * z2);
          float t34 = fmaf(va.w, z3, va.z * z4);
          float t56 = fmaf(vb.y, z5, vb.x * z6);
          float t78 = fmaf(vb.w, z7, vb.z * z8);
          float T14 = fmaf(t34, p12, t12 * p34);
          float T58 = fmaf(t78, p56, t56 * p78);
          a1 = fmaf(T14 * p5678, r, a1);
          a1 = fmaf(T58 * p1234, r, a1);
        }
      }
      float u0 = Vsum + a0;        // u = sum v - 2 sum v*rcp(z)
      float u1 = Vsum + a1;
      u0 += __shfl_xor(u0, 1); u0 += __shfl_xor(u0, 2); u0 += __shfl_xor(u0, 4);
      u1 += __shfl_xor(u1, 1); u1 += __shfl_xor(u1, 2); u1 += __shfl_xor(u1, 4);
      if (hc == 0) {
        // lg = 10*tanh(u) = 10 - 20*rcp(e^{2u}+1)
        float ex0 = __expf(2.f * u0);
        float ex1 = __expf(2.f * u1);
        float lg0 = fmaf(-20.f, __builtin_amdgcn_rcpf(ex0 + 1.f), 10.f);
        float lg1 = fmaf(-20.f, __builtin_amdgcn_rcpf(ex1 + 1.f), 10.f);
        lg_s[s0] = lg0; val_s[s0] = lg0 + g01.x;
        lg_s[s1] = lg1; val_s[s1] = lg1 + g01.y;
      }
    }
    __syncthreads();                                    // sync1

    // ---- phase B: per-wave argmax/max/expsum ----
    if (tid < NS) {
      float lgl = lg_s[tid];
      float v = val_s[tid]; int vi = tid; float ml = lgl;
      #pragma unroll
      for (int off = 1; off < 64; off <<= 1) {
        float ov = __shfl_xor(v, off);
        int   oi = __shfl_xor(vi, off);
        bool take = (ov > v) || (ov == v && oi < vi);
        v  = take ? ov : v;
        vi = take ? oi : vi;
        ml = fmaxf(ml, __shfl_xor(ml, off));
      }
      float e = __expf(lgl - ml);
      #pragma unroll
      for (int off = 1; off < 64; off <<= 1) e += __shfl_xor(e, off);
      if ((tid & 63) == 0) {
        red_v[tid >> 6] = v; red_i[tid >> 6] = vi;
        red_ml[tid >> 6] = ml; red_e[tid >> 6] = e;
      }
    }
    __syncthreads();                                    // sync2

    // ---- phase C ----
    float bvv = red_v[0]; int bii = red_i[0];
    #pragma unroll
    for (int w = 1; w < 4; ++w) {
      bool take = (red_v[w] > bvv) || (red_v[w] == bvv && red_i[w] < bii);
      bvv = take ? red_v[w] : bvv;
      bii = take ? red_i[w] : bii;
    }
    const int idx = bii;

    if (tid == 0) {
      float ml = fmaxf(fmaxf(red_ml[0], red_ml[1]), fmaxf(red_ml[2], red_ml[3]));
      float sum = 0.f;
      #pragma unroll
      for (int w = 0; w < 4; ++w) sum += red_e[w] * __expf(red_ml[w] - ml);
      logp += lg_s[idx] - (ml + logf(sum));
      idx_hist[i] = idx;
      out[2 * NB + b * NM + i] = (float)idx;
    }

    if (!m && (pr >> 1) == (idx >> 2)) { m = 1; pend = 1; }

    // one-time after step 0: fold e^{2*Qinit} into e2qb
    if (i == 0) {
      if (tid < NE) er[tid] = emb[((size_t)b * NS + idx) * NE + tid];
      __syncthreads();
      if (tid < NE) {
        float tv = 0.f;
        #pragma unroll 4
        for (int j = 0; j < NE; ++j) tv = fmaf(er[j], Wv[j * NE + tid], tv);
        Ts[tid] = tv;
      }
      __syncthreads();
      if (tid < NE) {
        float qi = 0.f;
        #pragma unroll 4
        for (int e2 = 0; e2 < NE; ++e2) qi = fmaf(Ts[e2], Wq[e2 * NH + tid], qi);
        e2qb *= __expf(2.0f * qi);
      }
    }

    // next step's e^{2q} = e2qb * EQB[idx]  (one mul per h, NO exp)
    if (tid < NH) qWp[PIDX(tid)] = e2qb * EQB_g[((size_t)b * NS + idx) * NH + tid];
    __syncthreads();                                    // sync3
  }

  if (tid == 0) out[b] = logp;

  // deferred reward
  if (tid < 64) {
    float term = 0.f;
    if (tid > 0) {
      int id = idx_hist[tid];
      int pv = idx_hist[tid - 1];
      float dx = node[((size_t)b * NS + id) * 4 + 0] - node[((size_t)b * NS + pv) * 4 + 2];
      float dy = node[((size_t)b * NS + id) * 4 + 1] - node[((size_t)b * NS + pv) * 4 + 3];
      term = sqrtf(dx * dx + dy * dy) + costs[(size_t)b * NS + pv] + costs[(size_t)b * NS + id];
    }
    #pragma unroll
    for (int off = 1; off < 64; off <<= 1) term += __shfl_xor(term, off);
    if (tid == 0) out[NB + b] = term;
  }
}

extern "C" void kernel_launch(void* const* d_in, const int* in_sizes, int n_in,
                              void* d_out, int out_size, void* d_ws, size_t ws_size,
                              hipStream_t stream) {
  const float* emb    = (const float*)d_in[0];
  const float* node   = (const float*)d_in[1];
  const float* costs  = (const float*)d_in[4];
  const float* init_w = (const float*)d_in[5];
  const float* Whc    = (const float*)d_in[6];
  const float* bhc    = (const float*)d_in[7];
  const float* Wv     = (const float*)d_in[8];
  const float* bv     = (const float*)d_in[9];
  const float* Wq     = (const float*)d_in[10];
  const float* Wk     = (const float*)d_in[11];
  const float* vptr   = (const float*)d_in[12];
  float* out = (float*)d_out;

  float* ws    = (float*)d_ws;
  float* g     = ws;
  float* kp    = g + NB * NM * NS;
  float* QB    = kp + (size_t)NB * NS * NH;
  float* tmpB  = QB + (size_t)NB * NS * NH;
  float* qbase = tmpB + (size_t)NB * NS * NE;
  float* q0W   = qbase + NB * NH;

  gumbel_kernel<<<NB * NM, 256, 0, stream>>>(g);
  prep_kernel<<<NB, NE, 0, stream>>>(emb, init_w, Whc, bhc, Wv, bv, Wq, qbase, q0W);
  mm_kernel<<<NB * NS / 16, 256, 0, stream>>>(emb, Wk, kp);
  mm_kernel<<<NB * NS / 16, 256, 0, stream>>>(emb, Wv + NE * NE, tmpB);
  mm_kernel<<<NB * NS / 16, 256, 0, stream>>>(tmpB, Wq, QB);
  expqb_kernel<<<(NB * NS * NH) / 1024, 1024, 0, stream>>>(QB);
  decode_kernel<<<NB, 1024, 0, stream>>>(emb, node, costs, Wv, Wq, vptr,
                                         g, kp, QB, qbase, q0W, out);
}